// Round 8
// baseline (139.640 us; speedup 1.0000x reference)
//
#include <hip/hip_runtime.h>

#define HIDDEN 4096
#define RANK   256
#define G      16     // HIDDEN / RANK
#define TW     2      // tokens per wave
#define NTH    256    // 4 waves/block, small blocks -> many independent blocks/CU

typedef _Float16 h2d __attribute__((ext_vector_type(2)));

__device__ __forceinline__ unsigned int pkf16(float a, float b) {
    auto h = __builtin_amdgcn_cvt_pkrtz(a, b);
    return __builtin_bit_cast(unsigned int, h);
}
__device__ __forceinline__ float dot2(unsigned int a, unsigned int b, float c) {
    return __builtin_amdgcn_fdot2(__builtin_bit_cast(h2d, a),
                                  __builtin_bit_cast(h2d, b), c, false);
}

// ---------------------------------------------------------------------------
// pack: Mp[pr*256 + k] = {f16 M[2pr][k], f16 M[2pr+1][k]}   (128 KB, once)
// ---------------------------------------------------------------------------
__global__ __launch_bounds__(256)
void mora_pack(const float* __restrict__ Mg, unsigned int* __restrict__ Mp) {
    const int idx = blockIdx.x * 256 + threadIdx.x;    // 0..32767
    const int pr  = idx >> 8;
    const int k   = idx & 255;
    Mp[idx] = pkf16(Mg[(size_t)(2 * pr) * RANK + k],
                    Mg[(size_t)(2 * pr + 1) * RANK + k]);
}

// ---------------------------------------------------------------------------
// main: barrier-free. Each wave owns TW=2 tokens end-to-end; M is read from
// L2 (packed f16) with coalesced b128 loads; comp lives in registers and is
// broadcast via v_readlane into v_dot2_f32_f16.
// ---------------------------------------------------------------------------
__global__ __launch_bounds__(NTH, 8)
void mora_v8(const float* __restrict__ x,          // [T, HIDDEN]
             const unsigned int* __restrict__ Mp,  // [128][256] packed f16 pairs
             float* __restrict__ out)              // [T, HIDDEN]
{
    __shared__ float ost[NTH / 64][RANK];          // 4 KiB, per-wave private

    const int  tid  = threadIdx.x;
    const int  w    = tid >> 6;
    const int  l    = tid & 63;
    const long tok0 = (long)blockIdx.x * (NTH / 64 * TW) + (long)w * TW;

    // ---- phase 1: comp in registers; lane l owns rows 4l..4l+3 ----
    unsigned int cp0[TW], cp1[TW];
    #pragma unroll
    for (int t = 0; t < TW; ++t) {
        const float4* xr = (const float4*)(x + (tok0 + t) * HIDDEN);
        float4 e = xr[l];
        float4 o = xr[l + 64];
        #pragma unroll
        for (int gi = 1; gi < G / 2; ++gi) {          // paired tree: 2 chains
            const float4 a = xr[l + (2 * gi) * 64];
            const float4 b = xr[l + (2 * gi + 1) * 64];
            e.x += a.x; e.y += a.y; e.z += a.z; e.w += a.w;
            o.x += b.x; o.y += b.y; o.z += b.z; o.w += b.w;
        }
        e.x += o.x; e.y += o.y; e.z += o.z; e.w += o.w;
        cp0[t] = pkf16(e.x, e.y);
        cp1[t] = pkf16(e.z, e.w);
    }

    // ---- phase 2: acc[t][c] = sum_r comp[t][r] * M[r][4l+c] ----
    float acc[TW][4];
    #pragma unroll
    for (int t = 0; t < TW; ++t) {
        acc[t][0] = 0.f; acc[t][1] = 0.f; acc[t][2] = 0.f; acc[t][3] = 0.f;
    }

    const uint4* Mp4 = (const uint4*)Mp;   // row-pair stride = 64 uint4
    #pragma unroll 4
    for (int i = 0; i < 32; ++i) {
        const uint4 m0 = Mp4[(4 * i + 0) * 64 + l];   // coalesced 1 KiB, L2-hot
        const uint4 m1 = Mp4[(4 * i + 1) * 64 + l];
        const uint4 m2 = Mp4[(4 * i + 2) * 64 + l];
        const uint4 m3 = Mp4[(4 * i + 3) * 64 + l];
        #pragma unroll
        for (int t = 0; t < TW; ++t) {
            const unsigned sA = (unsigned)__builtin_amdgcn_readlane((int)cp0[t], 2 * i);
            const unsigned sB = (unsigned)__builtin_amdgcn_readlane((int)cp1[t], 2 * i);
            const unsigned sC = (unsigned)__builtin_amdgcn_readlane((int)cp0[t], 2 * i + 1);
            const unsigned sD = (unsigned)__builtin_amdgcn_readlane((int)cp1[t], 2 * i + 1);
            acc[t][0] = dot2(sA, m0.x, acc[t][0]);
            acc[t][1] = dot2(sA, m0.y, acc[t][1]);
            acc[t][2] = dot2(sA, m0.z, acc[t][2]);
            acc[t][3] = dot2(sA, m0.w, acc[t][3]);
            acc[t][0] = dot2(sB, m1.x, acc[t][0]);
            acc[t][1] = dot2(sB, m1.y, acc[t][1]);
            acc[t][2] = dot2(sB, m1.z, acc[t][2]);
            acc[t][3] = dot2(sB, m1.w, acc[t][3]);
            acc[t][0] = dot2(sC, m2.x, acc[t][0]);
            acc[t][1] = dot2(sC, m2.y, acc[t][1]);
            acc[t][2] = dot2(sC, m2.z, acc[t][2]);
            acc[t][3] = dot2(sC, m2.w, acc[t][3]);
            acc[t][0] = dot2(sD, m3.x, acc[t][0]);
            acc[t][1] = dot2(sD, m3.y, acc[t][1]);
            acc[t][2] = dot2(sD, m3.z, acc[t][2]);
            acc[t][3] = dot2(sD, m3.w, acc[t][3]);
        }
    }

    // ---- phase 3: per-wave LDS restage (no barrier) + coalesced splat stores
    #pragma unroll
    for (int t = 0; t < TW; ++t) {
        ((float4*)ost[w])[l] =
            make_float4(acc[t][0], acc[t][1], acc[t][2], acc[t][3]);
        float4* orow = (float4*)(out + (tok0 + t) * HIDDEN);
        #pragma unroll
        for (int s = 0; s < 16; ++s) {
            const float v = ost[w][(s << 4) + (l >> 2)];  // 4-lane bcast, no conflict
            orow[(s << 6) + l] = make_float4(v, v, v, v);
        }
    }
}

extern "C" void kernel_launch(void* const* d_in, const int* in_sizes, int n_in,
                              void* d_out, int out_size, void* d_ws, size_t ws_size,
                              hipStream_t stream) {
    const float* x = (const float*)d_in[0];
    const float* M = (const float*)d_in[1];
    float* out     = (float*)d_out;
    unsigned int* Mp = (unsigned int*)d_ws;     // 128 KiB packed M

    const int T = in_sizes[0] / HIDDEN;         // 16384 tokens

    hipLaunchKernelGGL(mora_pack, dim3(128), dim3(256), 0, stream, M, Mp);
    hipLaunchKernelGGL(mora_v8, dim3(T / (NTH / 64 * TW)), dim3(NTH), 0, stream,
                       x, Mp, out);
}

// Round 9
// 115.554 us; speedup vs baseline: 1.2084x; 1.2084x over previous
//
#include <hip/hip_runtime.h>

#define HIDDEN 4096
#define RANK   256
#define G      16     // HIDDEN / RANK
#define TW     2      // tokens per wave in expand

typedef _Float16 h2d __attribute__((ext_vector_type(2)));
typedef float    f4v __attribute__((ext_vector_type(4)));

__device__ __forceinline__ unsigned int pkf16(float a, float b) {
    auto h = __builtin_amdgcn_cvt_pkrtz(a, b);
    return __builtin_bit_cast(unsigned int, h);
}
__device__ __forceinline__ float dot2(unsigned int a, unsigned int b, float c) {
    return __builtin_amdgcn_fdot2(__builtin_bit_cast(h2d, a),
                                  __builtin_bit_cast(h2d, b), c, false);
}

// ---------------------------------------------------------------------------
// pack: Mp[pr*256 + k] = {f16 M[2pr][k], f16 M[2pr+1][k]}   (128 KB, once)
// ---------------------------------------------------------------------------
__global__ __launch_bounds__(256)
void mora_pack(const float* __restrict__ Mg, unsigned int* __restrict__ Mp) {
    const int idx = blockIdx.x * 256 + threadIdx.x;    // 0..32767
    const int pr  = idx >> 8;
    const int k   = idx & 255;
    Mp[idx] = pkf16(Mg[(size_t)(2 * pr) * RANK + k],
                    Mg[(size_t)(2 * pr + 1) * RANK + k]);
}

// ---------------------------------------------------------------------------
// k1: pure read-stream probe. Thread = one float4 of comp:
//     comp[t][4r4..4r4+3] = sum_gi x[t][gi*256 + ...]. 16 coalesced loads,
//     15 adds, 1 coalesced store. No LDS, no barriers, 4096 balanced blocks.
// ---------------------------------------------------------------------------
__global__ __launch_bounds__(256)
void mora_compress(const float* __restrict__ x,     // [T, HIDDEN]
                   float* __restrict__ comp)        // [T, RANK]
{
    const long i  = (long)blockIdx.x * 256 + threadIdx.x;  // 0..1048575
    const long t  = i >> 6;
    const int  r4 = (int)(i & 63);

    const float4* xr = (const float4*)(x + t * HIDDEN) + r4;
    float4 e = xr[0];
    float4 o = xr[64];
    #pragma unroll
    for (int gi = 1; gi < G / 2; ++gi) {      // two independent chains (ILP)
        const float4 a = xr[(2 * gi) * 64];
        const float4 b = xr[(2 * gi + 1) * 64];
        e.x += a.x; e.y += a.y; e.z += a.z; e.w += a.w;
        o.x += b.x; o.y += b.y; o.z += b.z; o.w += b.w;
    }
    e.x += o.x; e.y += o.y; e.z += o.z; e.w += o.w;
    ((float4*)(comp + t * RANK))[r4] = e;
}

// ---------------------------------------------------------------------------
// k2: write-stream probe. Wave owns TW tokens: read comp (L2-hot, 1 KiB
//     coalesced), dot2 against packed-f16 M from L2, NONTEMPORAL splat
//     stores (out bypasses L2/L3 -> x stays L3-resident for next replay).
// ---------------------------------------------------------------------------
__global__ __launch_bounds__(256, 8)
void mora_expand(const float* __restrict__ comp,        // [T, RANK]
                 const unsigned int* __restrict__ Mp,   // [128][256] f16 pairs
                 float* __restrict__ out)               // [T, HIDDEN]
{
    __shared__ float ost[4][RANK];          // per-wave private, no barriers

    const int  tid  = threadIdx.x;
    const int  w    = tid >> 6;
    const int  l    = tid & 63;
    const long tok0 = (long)blockIdx.x * (4 * TW) + (long)w * TW;

    // comp -> registers, repacked to f16 pairs (lane l owns rows 4l..4l+3)
    unsigned int cp0[TW], cp1[TW];
    #pragma unroll
    for (int t = 0; t < TW; ++t) {
        const float4 c = ((const float4*)(comp + (tok0 + t) * RANK))[l];
        cp0[t] = pkf16(c.x, c.y);
        cp1[t] = pkf16(c.z, c.w);
    }

    float acc[TW][4];
    #pragma unroll
    for (int t = 0; t < TW; ++t) {
        acc[t][0] = 0.f; acc[t][1] = 0.f; acc[t][2] = 0.f; acc[t][3] = 0.f;
    }

    const uint4* Mp4 = (const uint4*)Mp;    // pair-row stride = 64 uint4
    #pragma unroll 4
    for (int i = 0; i < 32; ++i) {
        const uint4 m0 = Mp4[(4 * i + 0) * 64 + l];   // coalesced 1 KiB, L2-hot
        const uint4 m1 = Mp4[(4 * i + 1) * 64 + l];
        const uint4 m2 = Mp4[(4 * i + 2) * 64 + l];
        const uint4 m3 = Mp4[(4 * i + 3) * 64 + l];
        #pragma unroll
        for (int t = 0; t < TW; ++t) {
            const unsigned sA = (unsigned)__builtin_amdgcn_readlane((int)cp0[t], 2 * i);
            const unsigned sB = (unsigned)__builtin_amdgcn_readlane((int)cp1[t], 2 * i);
            const unsigned sC = (unsigned)__builtin_amdgcn_readlane((int)cp0[t], 2 * i + 1);
            const unsigned sD = (unsigned)__builtin_amdgcn_readlane((int)cp1[t], 2 * i + 1);
            acc[t][0] = dot2(sA, m0.x, acc[t][0]);
            acc[t][1] = dot2(sA, m0.y, acc[t][1]);
            acc[t][2] = dot2(sA, m0.z, acc[t][2]);
            acc[t][3] = dot2(sA, m0.w, acc[t][3]);
            acc[t][0] = dot2(sB, m1.x, acc[t][0]);
            acc[t][1] = dot2(sB, m1.y, acc[t][1]);
            acc[t][2] = dot2(sB, m1.z, acc[t][2]);
            acc[t][3] = dot2(sB, m1.w, acc[t][3]);
            acc[t][0] = dot2(sC, m2.x, acc[t][0]);
            acc[t][1] = dot2(sC, m2.y, acc[t][1]);
            acc[t][2] = dot2(sC, m2.z, acc[t][2]);
            acc[t][3] = dot2(sC, m2.w, acc[t][3]);
            acc[t][0] = dot2(sD, m3.x, acc[t][0]);
            acc[t][1] = dot2(sD, m3.y, acc[t][1]);
            acc[t][2] = dot2(sD, m3.z, acc[t][2]);
            acc[t][3] = dot2(sD, m3.w, acc[t][3]);
        }
    }

    // restage per wave, then NONTEMPORAL coalesced splat stores
    #pragma unroll
    for (int t = 0; t < TW; ++t) {
        ((float4*)ost[w])[l] =
            make_float4(acc[t][0], acc[t][1], acc[t][2], acc[t][3]);
        f4v* orow = (f4v*)(out + (tok0 + t) * HIDDEN);
        #pragma unroll
        for (int s = 0; s < 16; ++s) {
            const float v = ost[w][(s << 4) + (l >> 2)];  // 4-lane bcast, no conflict
            const f4v sp = {v, v, v, v};
            __builtin_nontemporal_store(sp, orow + (s << 6) + l);
        }
    }
}

extern "C" void kernel_launch(void* const* d_in, const int* in_sizes, int n_in,
                              void* d_out, int out_size, void* d_ws, size_t ws_size,
                              hipStream_t stream) {
    const float* x = (const float*)d_in[0];
    const float* M = (const float*)d_in[1];
    float* out     = (float*)d_out;

    unsigned int* Mp   = (unsigned int*)d_ws;                  // 128 KiB
    float*        comp = (float*)((char*)d_ws + 131072);       // 16 MiB

    const int T = in_sizes[0] / HIDDEN;     // 16384 tokens

    hipLaunchKernelGGL(mora_pack, dim3(128), dim3(256), 0, stream, M, Mp);
    hipLaunchKernelGGL(mora_compress, dim3(T * (RANK / 4) / 256), dim3(256),
                       0, stream, x, comp);
    hipLaunchKernelGGL(mora_expand, dim3(T / (4 * TW)), dim3(256), 0, stream,
                       comp, Mp, out);
}